// Round 12
// baseline (447.658 us; speedup 1.0000x reference)
//
#include <hip/hip_runtime.h>

#define N_SRC 100000
#define N_DST 20000
#define NE 640000
#define IN_F 256
#define NH 4
#define DF 32
#define NCOL 128  /* NH*DF */

// ---------------- K0: fold attn vectors into W (fp64) ----------------
// Wlr_t[j][k] = sum_d W[k][(j&3)*32+d] * attn_{l:j<4, r:j>=4}[(j&3)*32+d]
__global__ void k_prep(const float* __restrict__ W,
                       const float* __restrict__ attn_l,
                       const float* __restrict__ attn_r,
                       double* __restrict__ Wlr_t) {
    int k = threadIdx.x;  // 256 threads
    for (int j = 0; j < 8; ++j) {
        const float* attn = (j < 4) ? attn_l : attn_r;
        int hh = j & 3;
        double s = 0.0;
        for (int d = 0; d < DF; ++d)
            s += (double)W[k * NCOL + hh * DF + d] * (double)attn[hh * DF + d];
        Wlr_t[(size_t)j * IN_F + k] = s;
    }
}

// ---------------- K1: h = x @ W (fp32) + exact fp64 scores + histogram ------
// 32-row tile, two 128-k halves. xs[32][132] = 16.9 KB ONLY (Wlr_t read
// straight from global/L1 — it's 16 KB, wave-broadcast 32 B chunks; staging
// it to LDS in r11 halved resident blocks for zero benefit).
// Score mapping (srow=tid>>3, sj=tid&7): 32x8 outputs, no cross-thread
// reduction; xs pad 132 keeps the 8-distinct-row reads conflict-free.
// GEMM k-order unchanged -> h bit-identical; score chain exact fp64 from x.
// N_SRC = 3125*32 exactly -> no bounds checks.
__global__ __launch_bounds__(256) void k_gemm(const float* __restrict__ x,
                                              const float* __restrict__ W,
                                              const double* __restrict__ Wlr_t,
                                              const int* __restrict__ dst_idx,
                                              float* __restrict__ h,
                                              double* __restrict__ el,
                                              double* __restrict__ er_src,
                                              int* __restrict__ cnt) {
    __shared__ float xs[32][132];    // 16.9 KB
    const int tid = threadIdx.x;
    const int row0 = blockIdx.x * 32;
    const int c0 = (tid & 31) * 4;   // gemm: 4 consecutive cols
    const int r0 = (tid >> 5) * 4;   // gemm: 4 consecutive rows
    const int srow = tid >> 3;       // score: row 0..31
    const int sj = tid & 7;          // score: output 0..7 (l:0-3, r:4-7)

    float acc[4][4];
#pragma unroll
    for (int j = 0; j < 4; ++j)
#pragma unroll
        for (int m = 0; m < 4; ++m) acc[j][m] = 0.f;
    double sacc = 0.0;

    for (int half = 0; half < 2; ++half) {
        const int kbase = half * 128;
        if (half) __syncthreads();  // all xs readers of prev half done
        // stage 32 rows x 128 k, coalesced
#pragma unroll
        for (int t = 0; t < 4; ++t) {
            int i = t * 256 + tid;
            int r = i >> 5;
            int q = i & 31;
            *((float4*)&xs[r][q * 4]) =
                *((const float4*)(x + (size_t)(row0 + r) * IN_F + kbase + q * 4));
        }
        __syncthreads();

        // ---- GEMM inner (unchanged math/order) ----
#pragma unroll 4
        for (int kq = 0; kq < 128; kq += 4) {
            const float* wp = W + (size_t)(kbase + kq) * NCOL + c0;
            float4 w0 = *((const float4*)(wp));
            float4 w1 = *((const float4*)(wp + NCOL));
            float4 w2 = *((const float4*)(wp + 2 * NCOL));
            float4 w3 = *((const float4*)(wp + 3 * NCOL));
#pragma unroll
            for (int j = 0; j < 4; ++j) {
                float4 xv = *((const float4*)&xs[r0 + j][kq]);
                acc[j][0] += xv.x * w0.x + xv.y * w1.x + xv.z * w2.x + xv.w * w3.x;
                acc[j][1] += xv.x * w0.y + xv.y * w1.y + xv.z * w2.y + xv.w * w3.y;
                acc[j][2] += xv.x * w0.z + xv.y * w1.z + xv.z * w2.z + xv.w * w3.z;
                acc[j][3] += xv.x * w0.w + xv.y * w1.w + xv.z * w2.w + xv.w * w3.w;
            }
        }

        // ---- score inner: sacc += dot(x[srow][kbase..], Wlr[sj][kbase..]) ----
        {
            const double* wp = Wlr_t + (size_t)sj * IN_F + kbase;  // L1-resident
#pragma unroll 4
            for (int k = 0; k < 128; k += 4) {
                float4 xv = *((const float4*)&xs[srow][k]);
                double2 wa = *((const double2*)(wp + k));
                double2 wb = *((const double2*)(wp + k + 2));
                sacc += (double)xv.x * wa.x + (double)xv.y * wa.y
                      + (double)xv.z * wb.x + (double)xv.w * wb.y;
            }
        }
    }

    // write h
#pragma unroll
    for (int j = 0; j < 4; ++j) {
        int row = row0 + r0 + j;
        *((float4*)(h + (size_t)row * NCOL + c0)) =
            make_float4(acc[j][0], acc[j][1], acc[j][2], acc[j][3]);
    }

    // write scores
    {
        int row = row0 + srow;
        if (sj < 4) el[(size_t)row * NH + sj] = sacc;
        else        er_src[(size_t)row * NH + (sj - 4)] = sacc;
    }

    // histogram tail (cnt pre-zeroed by memset)
    for (int e = blockIdx.x * 256 + tid; e < NE; e += gridDim.x * 256)
        atomicAdd(cnt + dst_idx[e], 1);
}

// ---------------- k_scan: exclusive scan of cnt -> offsets; zero cursor ----
__global__ __launch_bounds__(1024) void k_scan(const int* __restrict__ cnt,
                                               int* __restrict__ offsets,
                                               int* __restrict__ cursor) {
    __shared__ int wsum[16];
    __shared__ int carry;
    int tid = threadIdx.x, lane = tid & 63, w = tid >> 6;
    if (tid == 0) carry = 0;
    __syncthreads();
    for (int base = 0; base < N_DST; base += 1024) {
        int i = base + tid;
        int v = (i < N_DST) ? cnt[i] : 0;
        int s = v;
#pragma unroll
        for (int off = 1; off < 64; off <<= 1) {
            int t = __shfl_up(s, off);
            if (lane >= off) s += t;
        }
        if (lane == 63) wsum[w] = s;
        __syncthreads();
        int wprefix = 0;
        for (int k = 0; k < w; ++k) wprefix += wsum[k];
        int incl = s + wprefix + carry;
        if (i < N_DST) {
            offsets[i + 1] = incl;
            cursor[i] = 0;
        }
        __syncthreads();
        if (tid == 1023) carry = incl;
        __syncthreads();
    }
    if (tid == 0) offsets[0] = 0;
}

__global__ __launch_bounds__(256) void k_fill(const int* __restrict__ src_idx,
                                              const int* __restrict__ dst_idx,
                                              const int* __restrict__ offsets,
                                              int* __restrict__ cursor,
                                              int* __restrict__ edge_src) {
    int gid = blockIdx.x * 256 + threadIdx.x;
    if (gid >= NE) return;
    int d = dst_idx[gid];
    int pos = offsets[d] + atomicAdd(cursor + d, 1);
    edge_src[pos] = src_idx[gid];
}

// ---------------- K5: fused S + normalize + weighted gather ----------------
// one WAVE per dst node (4 dst per 256-thread block); no barriers, no LDS.
__global__ __launch_bounds__(256) void k_fused(const int* __restrict__ offsets,
                                               const int* __restrict__ edge_src,
                                               const double* __restrict__ el,
                                               const double* __restrict__ er_src,
                                               const int* __restrict__ dst_to_src,
                                               const float* __restrict__ h,
                                               float* __restrict__ out) {
    const int lane = threadIdx.x & 63;
    const int d = blockIdx.x * 4 + (threadIdx.x >> 6);
    if (d >= N_DST) return;
    const int beg = offsets[d];
    const int deg = offsets[d + 1] - beg;

    const int srcd = dst_to_src[d];
    double er4[NH];
#pragma unroll
    for (int hh = 0; hh < NH; ++hh) er4[hh] = er_src[(size_t)srcd * NH + hh];

    // phase 1: S[h] via per-lane partial + wave butterfly (fp64)
    double sum4[NH] = {0.0, 0.0, 0.0, 0.0};
    for (int j = lane; j < deg; j += 64) {
        int s = edge_src[beg + j];
        const double* elp = el + (size_t)s * NH;
#pragma unroll
        for (int hh = 0; hh < NH; ++hh) {
            double e = elp[hh] + er4[hh];
            e = (e >= 0.0) ? e : 0.2 * e;
            sum4[hh] += e;
        }
    }
#pragma unroll
    for (int hh = 0; hh < NH; ++hh) {
#pragma unroll
        for (int m = 32; m >= 1; m >>= 1)
            sum4[hh] += __shfl_xor(sum4[hh], m);
    }

    // phase 2: 2 edges in flight; lane = (js, col quad cq)
    const int js = lane >> 5;
    const int cq = lane & 31;
    const int hd = cq >> 3;
    const double Sinv = (deg > 0) ? 1.0 / sum4[hd] : 0.0;

    double acc[4] = {0.0, 0.0, 0.0, 0.0};
    for (int j = js; j < deg; j += 2) {
        int s = edge_src[beg + j];
        double e = el[(size_t)s * NH + hd] + er4[hd];
        e = (e >= 0.0) ? e : 0.2 * e;
        double att = e * Sinv;
        float4 hv = *((const float4*)(h + (size_t)s * NCOL + cq * 4));
        acc[0] += att * (double)hv.x;
        acc[1] += att * (double)hv.y;
        acc[2] += att * (double)hv.z;
        acc[3] += att * (double)hv.w;
    }
#pragma unroll
    for (int m = 0; m < 4; ++m) acc[m] += __shfl_xor(acc[m], 32);

    if (lane < 32) {
        *((float4*)(out + (size_t)d * NCOL + lane * 4)) =
            make_float4((float)acc[0], (float)acc[1], (float)acc[2], (float)acc[3]);
    }
}

extern "C" void kernel_launch(void* const* d_in, const int* in_sizes, int n_in,
                              void* d_out, int out_size, void* d_ws, size_t ws_size,
                              hipStream_t stream) {
    const float* x      = (const float*)d_in[0];
    const float* W      = (const float*)d_in[1];
    const float* attn_l = (const float*)d_in[2];
    const float* attn_r = (const float*)d_in[3];
    const int* src_idx  = (const int*)d_in[4];
    const int* dst_idx  = (const int*)d_in[5];
    const int* dst_to_src = (const int*)d_in[6];
    float* out = (float*)d_out;

    char* p = (char*)d_ws;
    double* Wlr_t  = (double*)p;  p += (size_t)8 * IN_F * sizeof(double);     // 16 KB
    double* el     = (double*)p;  p += (size_t)N_SRC * NH * sizeof(double);   // 3.2 MB
    double* er_src = (double*)p;  p += (size_t)N_SRC * NH * sizeof(double);   // 3.2 MB
    float*  h      = (float*)p;   p += (size_t)N_SRC * NCOL * sizeof(float);  // 51.2 MB
    int*    cnt      = (int*)p;   p += (size_t)N_DST * sizeof(int);
    int*    offsets  = (int*)p;   p += (size_t)(N_DST + 1) * sizeof(int);
    int*    cursor   = (int*)p;   p += (size_t)N_DST * sizeof(int);
    int*    edge_src = (int*)p;   p += (size_t)NE * sizeof(int);

    hipMemsetAsync(cnt, 0, (size_t)N_DST * sizeof(int), stream);

    k_prep<<<1, 256, 0, stream>>>(W, attn_l, attn_r, Wlr_t);
    k_gemm<<<N_SRC / 32, 256, 0, stream>>>(x, W, Wlr_t, dst_idx, h, el, er_src, cnt);
    k_scan<<<1, 1024, 0, stream>>>(cnt, offsets, cursor);
    k_fill<<<(NE + 255) / 256, 256, 0, stream>>>(src_idx, dst_idx, offsets, cursor, edge_src);
    k_fused<<<N_DST / 4, 256, 0, stream>>>(offsets, edge_src, el, er_src, dst_to_src, h, out);
}

// Round 13
// 281.658 us; speedup vs baseline: 1.5894x; 1.5894x over previous
//
#include <hip/hip_runtime.h>

#define N_SRC 100000
#define N_DST 20000
#define NE 640000
#define IN_F 256
#define NH 4
#define DF 32
#define NCOL 128  /* NH*DF */

// ---------------- K0: fold attn vectors into W (fp64) ----------------
__global__ void k_prep(const float* __restrict__ W,
                       const float* __restrict__ attn_l,
                       const float* __restrict__ attn_r,
                       double* __restrict__ Wlr_t) {
    int k = threadIdx.x;  // 256 threads
    for (int j = 0; j < 8; ++j) {
        const float* attn = (j < 4) ? attn_l : attn_r;
        int hh = j & 3;
        double s = 0.0;
        for (int d = 0; d < DF; ++d)
            s += (double)W[k * NCOL + hh * DF + d] * (double)attn[hh * DF + d];
        Wlr_t[(size_t)j * IN_F + k] = s;
    }
}

// ---------------- K1: h = x @ W (fp32) + exact fp64 scores + histogram ------
// r11's proven version: Wlr staged in LDS (lgkm queue — keeping score reads
// OUT of the vmcnt queue; r12 showed global Wlr reads serialize the GEMM's
// W-load pipeline). xs[32][132] + wlds[8][258] = 33.4 KB -> 4 blocks/CU.
__global__ __launch_bounds__(256) void k_gemm(const float* __restrict__ x,
                                              const float* __restrict__ W,
                                              const double* __restrict__ Wlr_t,
                                              const int* __restrict__ dst_idx,
                                              float* __restrict__ h,
                                              double* __restrict__ el,
                                              double* __restrict__ er_src,
                                              int* __restrict__ cnt) {
    __shared__ float xs[32][132];    // 16.9 KB
    __shared__ double wlds[8][258];  // 16.5 KB
    const int tid = threadIdx.x;
    const int row0 = blockIdx.x * 32;
    const int c0 = (tid & 31) * 4;
    const int r0 = (tid >> 5) * 4;
    const int srow = tid >> 3;       // score: row 0..31
    const int sj = tid & 7;          // score: output 0..7 (l:0-3, r:4-7)

    for (int i = tid; i < 8 * IN_F; i += 256)
        wlds[i >> 8][i & 255] = Wlr_t[i];

    float acc[4][4];
#pragma unroll
    for (int j = 0; j < 4; ++j)
#pragma unroll
        for (int m = 0; m < 4; ++m) acc[j][m] = 0.f;
    double sacc = 0.0;

    for (int half = 0; half < 2; ++half) {
        const int kbase = half * 128;
        if (half) __syncthreads();
#pragma unroll
        for (int t = 0; t < 4; ++t) {
            int i = t * 256 + tid;
            int r = i >> 5;
            int q = i & 31;
            *((float4*)&xs[r][q * 4]) =
                *((const float4*)(x + (size_t)(row0 + r) * IN_F + kbase + q * 4));
        }
        __syncthreads();

#pragma unroll 4
        for (int kq = 0; kq < 128; kq += 4) {
            const float* wp = W + (size_t)(kbase + kq) * NCOL + c0;
            float4 w0 = *((const float4*)(wp));
            float4 w1 = *((const float4*)(wp + NCOL));
            float4 w2 = *((const float4*)(wp + 2 * NCOL));
            float4 w3 = *((const float4*)(wp + 3 * NCOL));
#pragma unroll
            for (int j = 0; j < 4; ++j) {
                float4 xv = *((const float4*)&xs[r0 + j][kq]);
                acc[j][0] += xv.x * w0.x + xv.y * w1.x + xv.z * w2.x + xv.w * w3.x;
                acc[j][1] += xv.x * w0.y + xv.y * w1.y + xv.z * w2.y + xv.w * w3.y;
                acc[j][2] += xv.x * w0.z + xv.y * w1.z + xv.z * w2.z + xv.w * w3.z;
                acc[j][3] += xv.x * w0.w + xv.y * w1.w + xv.z * w2.w + xv.w * w3.w;
            }
        }

        {
            const double* wp = &wlds[sj][kbase];
#pragma unroll 4
            for (int k = 0; k < 128; k += 4) {
                float4 xv = *((const float4*)&xs[srow][k]);
                double2 wa = *((const double2*)(wp + k));
                double2 wb = *((const double2*)(wp + k + 2));
                sacc += (double)xv.x * wa.x + (double)xv.y * wa.y
                      + (double)xv.z * wb.x + (double)xv.w * wb.y;
            }
        }
    }

#pragma unroll
    for (int j = 0; j < 4; ++j) {
        int row = row0 + r0 + j;
        *((float4*)(h + (size_t)row * NCOL + c0)) =
            make_float4(acc[j][0], acc[j][1], acc[j][2], acc[j][3]);
    }

    {
        int row = row0 + srow;
        if (sj < 4) el[(size_t)row * NH + sj] = sacc;
        else        er_src[(size_t)row * NH + (sj - 4)] = sacc;
    }

    for (int e = blockIdx.x * 256 + tid; e < NE; e += gridDim.x * 256)
        atomicAdd(cnt + dst_idx[e], 1);
}

// ---------------- k_scan: exclusive scan of cnt -> offsets; zero cursor ----
__global__ __launch_bounds__(1024) void k_scan(const int* __restrict__ cnt,
                                               int* __restrict__ offsets,
                                               int* __restrict__ cursor) {
    __shared__ int wsum[16];
    __shared__ int carry;
    int tid = threadIdx.x, lane = tid & 63, w = tid >> 6;
    if (tid == 0) carry = 0;
    __syncthreads();
    for (int base = 0; base < N_DST; base += 1024) {
        int i = base + tid;
        int v = (i < N_DST) ? cnt[i] : 0;
        int s = v;
#pragma unroll
        for (int off = 1; off < 64; off <<= 1) {
            int t = __shfl_up(s, off);
            if (lane >= off) s += t;
        }
        if (lane == 63) wsum[w] = s;
        __syncthreads();
        int wprefix = 0;
        for (int k = 0; k < w; ++k) wprefix += wsum[k];
        int incl = s + wprefix + carry;
        if (i < N_DST) {
            offsets[i + 1] = incl;
            cursor[i] = 0;
        }
        __syncthreads();
        if (tid == 1023) carry = incl;
        __syncthreads();
    }
    if (tid == 0) offsets[0] = 0;
}

__global__ __launch_bounds__(256) void k_fill(const int* __restrict__ src_idx,
                                              const int* __restrict__ dst_idx,
                                              const int* __restrict__ offsets,
                                              int* __restrict__ cursor,
                                              int* __restrict__ edge_src) {
    int gid = blockIdx.x * 256 + threadIdx.x;
    if (gid >= NE) return;
    int d = dst_idx[gid];
    int pos = offsets[d] + atomicAdd(cursor + d, 1);
    edge_src[pos] = src_idx[gid];
}

// ---------------- K5: fused S + normalize + weighted gather ----------------
// one WAVE per dst (4/block). Phase 1 computes e per edge and caches
// att = e/S + src in wave-private LDS (deg <= 64; rare overflow falls back
// to the global path). Phase 2: 2 LDS reads + 1 h-gather + 4 FMA per edge.
// No __syncthreads needed: LDS regions are wave-private (same-wave RAW is
// ordered via lgkmcnt by the compiler).
__global__ __launch_bounds__(256) void k_fused(const int* __restrict__ offsets,
                                               const int* __restrict__ edge_src,
                                               const double* __restrict__ el,
                                               const double* __restrict__ er_src,
                                               const int* __restrict__ dst_to_src,
                                               const float* __restrict__ h,
                                               float* __restrict__ out) {
    __shared__ double att_sh[4][4][68];  // [wave][head][edge], pad 68: conflict-free
    __shared__ int    s_sh[4][64];

    const int w = threadIdx.x >> 6;
    const int lane = threadIdx.x & 63;
    const int d = blockIdx.x * 4 + w;
    if (d >= N_DST) return;
    const int beg = offsets[d];
    const int deg = offsets[d + 1] - beg;

    const int srcd = dst_to_src[d];
    double2 era = *((const double2*)(er_src + (size_t)srcd * NH));
    double2 erb = *((const double2*)(er_src + (size_t)srcd * NH + 2));
    const double er0 = era.x, er1 = era.y, er2 = erb.x, er3 = erb.y;

    // phase 1: per-lane partials; stash first-iteration (j==lane) e and s
    double sum0 = 0.0, sum1 = 0.0, sum2 = 0.0, sum3 = 0.0;
    double e0r = 0.0, e1r = 0.0, e2r = 0.0, e3r = 0.0;
    int s_first = 0;
    for (int j = lane; j < deg; j += 64) {
        int s = edge_src[beg + j];
        double2 ela = *((const double2*)(el + (size_t)s * NH));
        double2 elb = *((const double2*)(el + (size_t)s * NH + 2));
        double e0 = ela.x + er0; e0 = (e0 >= 0.0) ? e0 : 0.2 * e0;
        double e1 = ela.y + er1; e1 = (e1 >= 0.0) ? e1 : 0.2 * e1;
        double e2 = elb.x + er2; e2 = (e2 >= 0.0) ? e2 : 0.2 * e2;
        double e3 = elb.y + er3; e3 = (e3 >= 0.0) ? e3 : 0.2 * e3;
        sum0 += e0; sum1 += e1; sum2 += e2; sum3 += e3;
        if (j == lane) { s_first = s; e0r = e0; e1r = e1; e2r = e2; e3r = e3; }
    }
#pragma unroll
    for (int m = 32; m >= 1; m >>= 1) {
        sum0 += __shfl_xor(sum0, m);
        sum1 += __shfl_xor(sum1, m);
        sum2 += __shfl_xor(sum2, m);
        sum3 += __shfl_xor(sum3, m);
    }

    // phase 1.5: cache att + src in wave-private LDS (edges 0..min(deg,64))
    if (lane < deg) {
        s_sh[w][lane] = s_first;
        att_sh[w][0][lane] = e0r / sum0;
        att_sh[w][1][lane] = e1r / sum1;
        att_sh[w][2][lane] = e2r / sum2;
        att_sh[w][3][lane] = e3r / sum3;
    }

    // phase 2: 2 edges in flight; lane = (js, col quad cq)
    const int js = lane >> 5;
    const int cq = lane & 31;
    const int hd = cq >> 3;
    const double Shd = (hd == 0) ? sum0 : (hd == 1) ? sum1 : (hd == 2) ? sum2 : sum3;
    const double erhd = (hd == 0) ? er0 : (hd == 1) ? er1 : (hd == 2) ? er2 : er3;

    double acc0 = 0.0, acc1 = 0.0, acc2 = 0.0, acc3 = 0.0;
    for (int j = js; j < deg; j += 2) {
        int s; double att;
        if (j < 64) {
            s = s_sh[w][j];
            att = att_sh[w][hd][j];
        } else {  // rare fallback (deg > 64)
            s = edge_src[beg + j];
            double e = el[(size_t)s * NH + hd] + erhd;
            e = (e >= 0.0) ? e : 0.2 * e;
            att = e / Shd;
        }
        float4 hv = *((const float4*)(h + (size_t)s * NCOL + cq * 4));
        acc0 += att * (double)hv.x;
        acc1 += att * (double)hv.y;
        acc2 += att * (double)hv.z;
        acc3 += att * (double)hv.w;
    }
    acc0 += __shfl_xor(acc0, 32);
    acc1 += __shfl_xor(acc1, 32);
    acc2 += __shfl_xor(acc2, 32);
    acc3 += __shfl_xor(acc3, 32);

    if (lane < 32) {
        *((float4*)(out + (size_t)d * NCOL + lane * 4)) =
            make_float4((float)acc0, (float)acc1, (float)acc2, (float)acc3);
    }
}

extern "C" void kernel_launch(void* const* d_in, const int* in_sizes, int n_in,
                              void* d_out, int out_size, void* d_ws, size_t ws_size,
                              hipStream_t stream) {
    const float* x      = (const float*)d_in[0];
    const float* W      = (const float*)d_in[1];
    const float* attn_l = (const float*)d_in[2];
    const float* attn_r = (const float*)d_in[3];
    const int* src_idx  = (const int*)d_in[4];
    const int* dst_idx  = (const int*)d_in[5];
    const int* dst_to_src = (const int*)d_in[6];
    float* out = (float*)d_out;

    char* p = (char*)d_ws;
    double* Wlr_t  = (double*)p;  p += (size_t)8 * IN_F * sizeof(double);
    double* el     = (double*)p;  p += (size_t)N_SRC * NH * sizeof(double);
    double* er_src = (double*)p;  p += (size_t)N_SRC * NH * sizeof(double);
    float*  h      = (float*)p;   p += (size_t)N_SRC * NCOL * sizeof(float);
    int*    cnt      = (int*)p;   p += (size_t)N_DST * sizeof(int);
    int*    offsets  = (int*)p;   p += (size_t)(N_DST + 1) * sizeof(int);
    int*    cursor   = (int*)p;   p += (size_t)N_DST * sizeof(int);
    int*    edge_src = (int*)p;   p += (size_t)NE * sizeof(int);

    hipMemsetAsync(cnt, 0, (size_t)N_DST * sizeof(int), stream);

    k_prep<<<1, 256, 0, stream>>>(W, attn_l, attn_r, Wlr_t);
    k_gemm<<<N_SRC / 32, 256, 0, stream>>>(x, W, Wlr_t, dst_idx, h, el, er_src, cnt);
    k_scan<<<1, 1024, 0, stream>>>(cnt, offsets, cursor);
    k_fill<<<(NE + 255) / 256, 256, 0, stream>>>(src_idx, dst_idx, offsets, cursor, edge_src);
    k_fused<<<N_DST / 4, 256, 0, stream>>>(offsets, edge_src, el, er_src, dst_to_src, h, out);
}

// Round 14
// 279.813 us; speedup vs baseline: 1.5998x; 1.0066x over previous
//
#include <hip/hip_runtime.h>

#define N_SRC 100000
#define N_DST 20000
#define NE 640000
#define IN_F 256
#define NH 4
#define DF 32
#define NCOL 128  /* NH*DF */

// ---------------- K0: fold attn vectors into W (fp64) ----------------
__global__ void k_prep(const float* __restrict__ W,
                       const float* __restrict__ attn_l,
                       const float* __restrict__ attn_r,
                       double* __restrict__ Wlr_t) {
    int k = threadIdx.x;  // 256 threads
    for (int j = 0; j < 8; ++j) {
        const float* attn = (j < 4) ? attn_l : attn_r;
        int hh = j & 3;
        double s = 0.0;
        for (int d = 0; d < DF; ++d)
            s += (double)W[k * NCOL + hh * DF + d] * (double)attn[hh * DF + d];
        Wlr_t[(size_t)j * IN_F + k] = s;
    }
}

// ---------------- K1: h = x @ W (fp32) + exact fp64 scores + histogram ------
// K chunked in 4x64: xs[32][68] (8.7 KB) + per-chunk wlds[8][66] (4.2 KB)
// = 12.9 KB LDS -> 8 blocks/CU = 32 waves/CU (HW max; VGPR 56 <= 64).
// Score reads stay in the LDS/lgkm queue (r12: global fp64 reads in the
// loop serialize the GEMM's vmcnt pipeline). k-order per output unchanged
// -> h and scores bit-identical to r11/r13.
// N_SRC = 3125*32 exactly -> no bounds checks.
__global__ __launch_bounds__(256) void k_gemm(const float* __restrict__ x,
                                              const float* __restrict__ W,
                                              const double* __restrict__ Wlr_t,
                                              const int* __restrict__ dst_idx,
                                              float* __restrict__ h,
                                              double* __restrict__ el,
                                              double* __restrict__ er_src,
                                              int* __restrict__ cnt) {
    __shared__ float xs[32][68];    // 8.7 KB (pad 68: score reads conflict-free)
    __shared__ double wlds[8][66];  // 4.2 KB (per-chunk slice of Wlr_t)
    const int tid = threadIdx.x;
    const int row0 = blockIdx.x * 32;
    const int c0 = (tid & 31) * 4;   // gemm: 4 consecutive cols
    const int r0 = (tid >> 5) * 4;   // gemm: 4 consecutive rows
    const int srow = tid >> 3;       // score: row 0..31
    const int sj = tid & 7;          // score: output 0..7 (l:0-3, r:4-7)

    float acc[4][4];
#pragma unroll
    for (int j = 0; j < 4; ++j)
#pragma unroll
        for (int m = 0; m < 4; ++m) acc[j][m] = 0.f;
    double sacc = 0.0;

    for (int chunk = 0; chunk < 4; ++chunk) {
        const int kbase = chunk * 64;
        if (chunk) __syncthreads();  // readers of previous chunk done
        // stage xs: 32 rows x 64 k = 512 float4, 2 per thread, coalesced
#pragma unroll
        for (int t = 0; t < 2; ++t) {
            int i = t * 256 + tid;
            int r = i >> 4;       // 0..31
            int q = i & 15;       // float4 within chunk
            *((float4*)&xs[r][q * 4]) =
                *((const float4*)(x + (size_t)(row0 + r) * IN_F + kbase + q * 4));
        }
        // stage wlds: 8 x 64 doubles, 2 per thread, coalesced per j-row
#pragma unroll
        for (int t = 0; t < 2; ++t) {
            int i = t * 256 + tid;
            int j = i >> 6;       // 0..7
            int k = i & 63;
            wlds[j][k] = Wlr_t[(size_t)j * IN_F + kbase + k];
        }
        __syncthreads();

        // ---- GEMM inner (unchanged math/order) ----
#pragma unroll 4
        for (int kq = 0; kq < 64; kq += 4) {
            const float* wp = W + (size_t)(kbase + kq) * NCOL + c0;
            float4 w0 = *((const float4*)(wp));
            float4 w1 = *((const float4*)(wp + NCOL));
            float4 w2 = *((const float4*)(wp + 2 * NCOL));
            float4 w3 = *((const float4*)(wp + 3 * NCOL));
#pragma unroll
            for (int j = 0; j < 4; ++j) {
                float4 xv = *((const float4*)&xs[r0 + j][kq]);
                acc[j][0] += xv.x * w0.x + xv.y * w1.x + xv.z * w2.x + xv.w * w3.x;
                acc[j][1] += xv.x * w0.y + xv.y * w1.y + xv.z * w2.y + xv.w * w3.y;
                acc[j][2] += xv.x * w0.z + xv.y * w1.z + xv.z * w2.z + xv.w * w3.z;
                acc[j][3] += xv.x * w0.w + xv.y * w1.w + xv.z * w2.w + xv.w * w3.w;
            }
        }

        // ---- score inner: sacc += dot(x[srow][kbase..+63], Wlr[sj][...]) ----
        {
#pragma unroll 4
            for (int k = 0; k < 64; k += 4) {
                float4 xv = *((const float4*)&xs[srow][k]);
                double2 wa = *((const double2*)&wlds[sj][k]);
                double2 wb = *((const double2*)&wlds[sj][k + 2]);
                sacc += (double)xv.x * wa.x + (double)xv.y * wa.y
                      + (double)xv.z * wb.x + (double)xv.w * wb.y;
            }
        }
    }

    // write h
#pragma unroll
    for (int j = 0; j < 4; ++j) {
        int row = row0 + r0 + j;
        *((float4*)(h + (size_t)row * NCOL + c0)) =
            make_float4(acc[j][0], acc[j][1], acc[j][2], acc[j][3]);
    }

    // write scores
    {
        int row = row0 + srow;
        if (sj < 4) el[(size_t)row * NH + sj] = sacc;
        else        er_src[(size_t)row * NH + (sj - 4)] = sacc;
    }

    // histogram tail (cnt pre-zeroed by memset)
    for (int e = blockIdx.x * 256 + tid; e < NE; e += gridDim.x * 256)
        atomicAdd(cnt + dst_idx[e], 1);
}

// ---------------- k_scan: exclusive scan of cnt -> offsets; zero cursor ----
__global__ __launch_bounds__(1024) void k_scan(const int* __restrict__ cnt,
                                               int* __restrict__ offsets,
                                               int* __restrict__ cursor) {
    __shared__ int wsum[16];
    __shared__ int carry;
    int tid = threadIdx.x, lane = tid & 63, w = tid >> 6;
    if (tid == 0) carry = 0;
    __syncthreads();
    for (int base = 0; base < N_DST; base += 1024) {
        int i = base + tid;
        int v = (i < N_DST) ? cnt[i] : 0;
        int s = v;
#pragma unroll
        for (int off = 1; off < 64; off <<= 1) {
            int t = __shfl_up(s, off);
            if (lane >= off) s += t;
        }
        if (lane == 63) wsum[w] = s;
        __syncthreads();
        int wprefix = 0;
        for (int k = 0; k < w; ++k) wprefix += wsum[k];
        int incl = s + wprefix + carry;
        if (i < N_DST) {
            offsets[i + 1] = incl;
            cursor[i] = 0;
        }
        __syncthreads();
        if (tid == 1023) carry = incl;
        __syncthreads();
    }
    if (tid == 0) offsets[0] = 0;
}

__global__ __launch_bounds__(256) void k_fill(const int* __restrict__ src_idx,
                                              const int* __restrict__ dst_idx,
                                              const int* __restrict__ offsets,
                                              int* __restrict__ cursor,
                                              int* __restrict__ edge_src) {
    int gid = blockIdx.x * 256 + threadIdx.x;
    if (gid >= NE) return;
    int d = dst_idx[gid];
    int pos = offsets[d] + atomicAdd(cursor + d, 1);
    edge_src[pos] = src_idx[gid];
}

// ---------------- K5: fused S + normalize + weighted gather ----------------
// one WAVE per dst (4/block); att + src cached in wave-private LDS.
__global__ __launch_bounds__(256) void k_fused(const int* __restrict__ offsets,
                                               const int* __restrict__ edge_src,
                                               const double* __restrict__ el,
                                               const double* __restrict__ er_src,
                                               const int* __restrict__ dst_to_src,
                                               const float* __restrict__ h,
                                               float* __restrict__ out) {
    __shared__ double att_sh[4][4][68];
    __shared__ int    s_sh[4][64];

    const int w = threadIdx.x >> 6;
    const int lane = threadIdx.x & 63;
    const int d = blockIdx.x * 4 + w;
    if (d >= N_DST) return;
    const int beg = offsets[d];
    const int deg = offsets[d + 1] - beg;

    const int srcd = dst_to_src[d];
    double2 era = *((const double2*)(er_src + (size_t)srcd * NH));
    double2 erb = *((const double2*)(er_src + (size_t)srcd * NH + 2));
    const double er0 = era.x, er1 = era.y, er2 = erb.x, er3 = erb.y;

    double sum0 = 0.0, sum1 = 0.0, sum2 = 0.0, sum3 = 0.0;
    double e0r = 0.0, e1r = 0.0, e2r = 0.0, e3r = 0.0;
    int s_first = 0;
    for (int j = lane; j < deg; j += 64) {
        int s = edge_src[beg + j];
        double2 ela = *((const double2*)(el + (size_t)s * NH));
        double2 elb = *((const double2*)(el + (size_t)s * NH + 2));
        double e0 = ela.x + er0; e0 = (e0 >= 0.0) ? e0 : 0.2 * e0;
        double e1 = ela.y + er1; e1 = (e1 >= 0.0) ? e1 : 0.2 * e1;
        double e2 = elb.x + er2; e2 = (e2 >= 0.0) ? e2 : 0.2 * e2;
        double e3 = elb.y + er3; e3 = (e3 >= 0.0) ? e3 : 0.2 * e3;
        sum0 += e0; sum1 += e1; sum2 += e2; sum3 += e3;
        if (j == lane) { s_first = s; e0r = e0; e1r = e1; e2r = e2; e3r = e3; }
    }
#pragma unroll
    for (int m = 32; m >= 1; m >>= 1) {
        sum0 += __shfl_xor(sum0, m);
        sum1 += __shfl_xor(sum1, m);
        sum2 += __shfl_xor(sum2, m);
        sum3 += __shfl_xor(sum3, m);
    }

    if (lane < deg) {
        s_sh[w][lane] = s_first;
        att_sh[w][0][lane] = e0r / sum0;
        att_sh[w][1][lane] = e1r / sum1;
        att_sh[w][2][lane] = e2r / sum2;
        att_sh[w][3][lane] = e3r / sum3;
    }

    const int js = lane >> 5;
    const int cq = lane & 31;
    const int hd = cq >> 3;
    const double Shd = (hd == 0) ? sum0 : (hd == 1) ? sum1 : (hd == 2) ? sum2 : sum3;
    const double erhd = (hd == 0) ? er0 : (hd == 1) ? er1 : (hd == 2) ? er2 : er3;

    double acc0 = 0.0, acc1 = 0.0, acc2 = 0.0, acc3 = 0.0;
    for (int j = js; j < deg; j += 2) {
        int s; double att;
        if (j < 64) {
            s = s_sh[w][j];
            att = att_sh[w][hd][j];
        } else {
            s = edge_src[beg + j];
            double e = el[(size_t)s * NH + hd] + erhd;
            e = (e >= 0.0) ? e : 0.2 * e;
            att = e / Shd;
        }
        float4 hv = *((const float4*)(h + (size_t)s * NCOL + cq * 4));
        acc0 += att * (double)hv.x;
        acc1 += att * (double)hv.y;
        acc2 += att * (double)hv.z;
        acc3 += att * (double)hv.w;
    }
    acc0 += __shfl_xor(acc0, 32);
    acc1 += __shfl_xor(acc1, 32);
    acc2 += __shfl_xor(acc2, 32);
    acc3 += __shfl_xor(acc3, 32);

    if (lane < 32) {
        *((float4*)(out + (size_t)d * NCOL + lane * 4)) =
            make_float4((float)acc0, (float)acc1, (float)acc2, (float)acc3);
    }
}

extern "C" void kernel_launch(void* const* d_in, const int* in_sizes, int n_in,
                              void* d_out, int out_size, void* d_ws, size_t ws_size,
                              hipStream_t stream) {
    const float* x      = (const float*)d_in[0];
    const float* W      = (const float*)d_in[1];
    const float* attn_l = (const float*)d_in[2];
    const float* attn_r = (const float*)d_in[3];
    const int* src_idx  = (const int*)d_in[4];
    const int* dst_idx  = (const int*)d_in[5];
    const int* dst_to_src = (const int*)d_in[6];
    float* out = (float*)d_out;

    char* p = (char*)d_ws;
    double* Wlr_t  = (double*)p;  p += (size_t)8 * IN_F * sizeof(double);
    double* el     = (double*)p;  p += (size_t)N_SRC * NH * sizeof(double);
    double* er_src = (double*)p;  p += (size_t)N_SRC * NH * sizeof(double);
    float*  h      = (float*)p;   p += (size_t)N_SRC * NCOL * sizeof(float);
    int*    cnt      = (int*)p;   p += (size_t)N_DST * sizeof(int);
    int*    offsets  = (int*)p;   p += (size_t)(N_DST + 1) * sizeof(int);
    int*    cursor   = (int*)p;   p += (size_t)N_DST * sizeof(int);
    int*    edge_src = (int*)p;   p += (size_t)NE * sizeof(int);

    hipMemsetAsync(cnt, 0, (size_t)N_DST * sizeof(int), stream);

    k_prep<<<1, 256, 0, stream>>>(W, attn_l, attn_r, Wlr_t);
    k_gemm<<<N_SRC / 32, 256, 0, stream>>>(x, W, Wlr_t, dst_idx, h, el, er_src, cnt);
    k_scan<<<1, 1024, 0, stream>>>(cnt, offsets, cursor);
    k_fill<<<(NE + 255) / 256, 256, 0, stream>>>(src_idx, dst_idx, offsets, cursor, edge_src);
    k_fused<<<N_DST / 4, 256, 0, stream>>>(offsets, edge_src, el, er_src, dst_to_src, h, out);
}